// Round 10
// baseline (171.458 us; speedup 1.0000x reference)
//
#include <hip/hip_runtime.h>
#include <hip/hip_bf16.h>

#define NTOK 2048      // B*T
#define DM 1024
#define NEXP 8
#define FFN 4096
#define BM 64
#define BN 64
#define BK 64
#define ASTR 72        // A-tile LDS row stride (bf16)
#define MTS 4          // m-tile slots (4*64=256 cap, grid-stride beyond)
#define G2_SPLIT 4

typedef __bf16 bf16x8 __attribute__((ext_vector_type(8)));
typedef __bf16 bf16x4 __attribute__((ext_vector_type(4)));
typedef float f32x4 __attribute__((ext_vector_type(4)));

__device__ __forceinline__ bf16x8 zero8() {
  bf16x8 z;
#pragma unroll
  for (int j = 0; j < 8; j++) z[j] = (__bf16)0.f;
  return z;
}

// 4x4 f32 transpose across lanes {l, l^16, l^32, l^48}. (verified R2-R9)
__device__ __forceinline__ void xpose4(float v[4], int quad) {
  const bool b0 = quad & 1;
  const bool b1 = (quad & 2) != 0;
  float t;
  t = __shfl_xor(b0 ? v[0] : v[1], 16, 64); if (b0) v[0] = t; else v[1] = t;
  t = __shfl_xor(b0 ? v[2] : v[3], 16, 64); if (b0) v[2] = t; else v[3] = t;
  t = __shfl_xor(b1 ? v[0] : v[2], 32, 64); if (b1) v[0] = t; else v[2] = t;
  t = __shfl_xor(b1 ? v[1] : v[3], 32, 64); if (b1) v[1] = t; else v[3] = t;
}

// Swizzled B-tile read (row stride 144 B, XOR 16B-block by row>>3): verified R5-R9.
__device__ __forceinline__ bf16x8 readB(const char* BsB, int row, int kh, int quad) {
  return *(const bf16x8*)(BsB + row * 144 +
                          ((((kh << 2) + quad) ^ (row >> 3)) << 4));
}

// Store one transposed fp32 float4 -> bf16x4 into swizzled B tile (verified R5-R9).
#define STOREB(bb, v4, it) do {                                          \
    float vv[4] = {(v4).x, (v4).y, (v4).z, (v4).w};                      \
    xpose4(vv, quad);                                                    \
    bf16x4 o;                                                            \
    o[0] = (__bf16)vv[0]; o[1] = (__bf16)vv[1];                          \
    o[2] = (__bf16)vv[2]; o[3] = (__bf16)vv[3];                          \
    *(bf16x4*)((bb) + (((((it) << 1) + (w >> 1)) ^ rsw) << 4)) = o;      \
  } while (0)

// ---------------- router + bf16 compact gather ----------------
__global__ __launch_bounds__(256) void router_gather(
    const float* __restrict__ x, const int* __restrict__ mask,
    const float* __restrict__ rw, int* __restrict__ counts,
    int* __restrict__ tlist, float* __restrict__ gateE,
    __bf16* __restrict__ xg)
{
  int wid = threadIdx.x >> 6, lane = threadIdx.x & 63;
  int t = blockIdx.x * 4 + wid;

  const float* xr = x + (size_t)t * DM;
  float xv[16];
#pragma unroll
  for (int i = 0; i < 4; i++) {
    const float4 v = *(const float4*)(xr + lane * 16 + i * 4);
    xv[i * 4 + 0] = v.x; xv[i * 4 + 1] = v.y;
    xv[i * 4 + 2] = v.z; xv[i * 4 + 3] = v.w;
  }

  float acc[NEXP];
#pragma unroll
  for (int e = 0; e < NEXP; e++) {
    float a = 0.f;
    const float* rwe = rw + e * DM + lane * 16;
#pragma unroll
    for (int i = 0; i < 4; i++) {
      const float4 r = *(const float4*)(rwe + i * 4);
      a += xv[i*4+0]*r.x + xv[i*4+1]*r.y + xv[i*4+2]*r.z + xv[i*4+3]*r.w;
    }
    acc[e] = a;
  }
#pragma unroll
  for (int e = 0; e < NEXP; e++)
#pragma unroll
    for (int s = 1; s < 64; s <<= 1) acc[e] += __shfl_xor(acc[e], s, 64);

  int pack = -1;
  if (lane == 0 && mask[t] != 0) {
    float m = acc[0]; int am = 0;
#pragma unroll
    for (int e = 1; e < NEXP; e++) if (acc[e] > m) { m = acc[e]; am = e; }
    float s = 0.f;
#pragma unroll
    for (int e = 0; e < NEXP; e++) s += __expf(acc[e] - m);
    int slot = atomicAdd(&counts[am], 1);
    tlist[am * NTOK + slot] = t;
    gateE[am * NTOK + slot] = 1.0f / s;
    pack = am * NTOK + slot;
  }
  pack = __shfl(pack, 0, 64);
  if (pack >= 0) {
    __bf16* dst = xg + (size_t)pack * DM + lane * 16;
    bf16x8 o0, o1;
#pragma unroll
    for (int j = 0; j < 8; j++) {
      o0[j] = (__bf16)xv[j];
      o1[j] = (__bf16)xv[8 + j];
    }
    *(bf16x8*)dst = o0;
    *(bf16x8*)(dst + 8) = o1;
  }
}

// ---------------- GEMM1: h[tok] = relu(xg_e @ w1[e]), BM=64 ----------------
__global__ __launch_bounds__(256, 4) void moe_gemm1(
    const __bf16* __restrict__ xg, const float* __restrict__ w1,
    const int* __restrict__ counts, const int* __restrict__ tlist,
    __bf16* __restrict__ h)
{
  int bx = blockIdx.x;
  int nt = bx & 63, mt = (bx >> 6) & (MTS - 1), e = bx >> 8;
  int cnt = counts[e];
  if (mt * BM >= cnt) return;
  int n0 = nt * BN;

  __shared__ __bf16 As[BM][ASTR];
  __shared__ char   Bs[64 * 144];
  __shared__ int    toks[BM];

  int tid = threadIdx.x, lane = tid & 63, w = tid >> 6;
  int wm = w >> 1, wn = w & 1;
  int r16 = lane & 15, quad = lane >> 4;
  int rsw = r16 >> 1;
  char* bb = Bs + ((r16 << 2) + quad) * 144 + ((w & 1) << 3);

  const __bf16* xge = xg + (size_t)e * NTOK * DM;
  const float*  w1e = w1 + (size_t)e * DM * FFN;

  int ar = tid >> 2;
  int ak = (tid & 3) << 4;
  const float* bptr = w1e + (size_t)(w * 4 + quad) * FFN + n0 + (r16 << 2);

  bf16x8 a0r[2], a1r[2];
  float4 br[2][4];

#define LOADG1(S, kb) do {                                                \
    a0r[S] = av ? *(const bf16x8*)(aptr + (kb))     : zero8();            \
    a1r[S] = av ? *(const bf16x8*)(aptr + (kb) + 8) : zero8();            \
    br[S][0] = *(const float4*)(bptr + (size_t)((kb) +  0) * FFN);        \
    br[S][1] = *(const float4*)(bptr + (size_t)((kb) + 16) * FFN);        \
    br[S][2] = *(const float4*)(bptr + (size_t)((kb) + 32) * FFN);        \
    br[S][3] = *(const float4*)(bptr + (size_t)((kb) + 48) * FFN);        \
  } while (0)

#define MFMA8() do {                                                      \
    _Pragma("unroll") for (int kh = 0; kh < 2; kh++) {                    \
      int ks = kh * 32 + (quad << 3);                                     \
      bf16x8 aA = *(const bf16x8*)&As[wm * 32 + r16][ks];                 \
      bf16x8 aB = *(const bf16x8*)&As[wm * 32 + 16 + r16][ks];            \
      bf16x8 bA = readB(Bs, wn * 32 + r16, kh, quad);                     \
      bf16x8 bB = readB(Bs, wn * 32 + 16 + r16, kh, quad);                \
      acc[0][0] = __builtin_amdgcn_mfma_f32_16x16x32_bf16(aA, bA, acc[0][0], 0, 0, 0); \
      acc[0][1] = __builtin_amdgcn_mfma_f32_16x16x32_bf16(aA, bB, acc[0][1], 0, 0, 0); \
      acc[1][0] = __builtin_amdgcn_mfma_f32_16x16x32_bf16(aB, bA, acc[1][0], 0, 0, 0); \
      acc[1][1] = __builtin_amdgcn_mfma_f32_16x16x32_bf16(aB, bB, acc[1][1], 0, 0, 0); \
    } } while (0)

#define STEP1(S, t) do {                                                  \
    *(bf16x8*)&As[ar][ak]     = a0r[S];                                   \
    *(bf16x8*)&As[ar][ak + 8] = a1r[S];                                   \
    STOREB(bb, br[S][0], 0); STOREB(bb, br[S][1], 1);                     \
    STOREB(bb, br[S][2], 2); STOREB(bb, br[S][3], 3);                     \
    __syncthreads();                                                      \
    if ((t) + 2 < 16) LOADG1(S, ((t) + 2) * BK);                          \
    MFMA8();                                                              \
    __syncthreads();                                                      \
  } while (0)

  for (int m0 = mt * BM; m0 < cnt; m0 += MTS * BM) {
    bool av = (m0 + ar) < cnt;
    const __bf16* aptr = xge + (size_t)(m0 + ar) * DM + ak;

    f32x4 acc[2][2] = {};
    LOADG1(0, 0);
    LOADG1(1, BK);
    for (int tt = 0; tt < 16; tt += 2) {
      STEP1(0, tt);
      STEP1(1, tt + 1);
    }

    if (tid < BM) toks[tid] = (m0 + tid < cnt) ? tlist[e * NTOK + m0 + tid] : -1;
    __syncthreads();

#pragma unroll
    for (int mf = 0; mf < 2; mf++) {
#pragma unroll
      for (int i = 0; i < 4; i++) {
        int row = wm * 32 + mf * 16 + (quad << 2) + i;
        int tok = toks[row];
        if (tok >= 0) {
          __bf16* hp = h + (size_t)tok * FFN + n0 + wn * 32 + r16;
          hp[0]  = (__bf16)fmaxf(acc[mf][0][i], 0.f);
          hp[16] = (__bf16)fmaxf(acc[mf][1][i], 0.f);
        }
      }
    }
    __syncthreads();   // toks/LDS reuse guard for next m-tile
  }
#undef STEP1
#undef LOADG1
}

// ------- GEMM2 (split-K=4): out[tok] += (h_e @ w2[e]) * gate ----------
__global__ __launch_bounds__(256, 4) void moe_gemm2(
    const __bf16* __restrict__ h, const float* __restrict__ w2,
    const int* __restrict__ counts, const int* __restrict__ tlist,
    const float* __restrict__ gateE, float* __restrict__ out)
{
  int bx = blockIdx.x;
  int nt = bx & 15, mt = (bx >> 4) & (MTS - 1), e = (bx >> 6) & 7, sp = bx >> 9;
  int cnt = counts[e];
  if (mt * BM >= cnt) return;
  int n0 = nt * BN;
  int ksp = sp * (FFN / G2_SPLIT);

  __shared__ __bf16 As[BM][ASTR];
  __shared__ char   Bs[64 * 144];
  __shared__ int    toks[BM];
  __shared__ float  gts[BM];

  int tid = threadIdx.x, lane = tid & 63, w = tid >> 6;
  int wm = w >> 1, wn = w & 1;
  int r16 = lane & 15, quad = lane >> 4;
  int rsw = r16 >> 1;
  char* bb = Bs + ((r16 << 2) + quad) * 144 + ((w & 1) << 3);

  const float* w2e = w2 + (size_t)e * FFN * DM;
  int ar = tid >> 2;
  int ak = (tid & 3) << 4;
  const float* bptr = w2e + (size_t)(ksp + w * 4 + quad) * DM + n0 + (r16 << 2);

  bf16x8 a0r[2], a1r[2];
  float4 br[2][4];

#define LOADG2(S, kb) do {                                                \
    a0r[S] = av ? *(const bf16x8*)(aptr + (kb))     : zero8();            \
    a1r[S] = av ? *(const bf16x8*)(aptr + (kb) + 8) : zero8();            \
    br[S][0] = *(const float4*)(bptr + (size_t)((kb) +  0) * DM);         \
    br[S][1] = *(const float4*)(bptr + (size_t)((kb) + 16) * DM);         \
    br[S][2] = *(const float4*)(bptr + (size_t)((kb) + 32) * DM);         \
    br[S][3] = *(const float4*)(bptr + (size_t)((kb) + 48) * DM);         \
  } while (0)

#define STEP2(S, t) do {                                                  \
    *(bf16x8*)&As[ar][ak]     = a0r[S];                                   \
    *(bf16x8*)&As[ar][ak + 8] = a1r[S];                                   \
    STOREB(bb, br[S][0], 0); STOREB(bb, br[S][1], 1);                     \
    STOREB(bb, br[S][2], 2); STOREB(bb, br[S][3], 3);                     \
    __syncthreads();                                                      \
    if ((t) + 2 < 16) LOADG2(S, ((t) + 2) * BK);                          \
    MFMA8();                                                              \
    __syncthreads();                                                      \
  } while (0)

  for (int m0 = mt * BM; m0 < cnt; m0 += MTS * BM) {
    if (tid < BM) {
      bool v = (m0 + tid) < cnt;
      toks[tid] = v ? tlist[e * NTOK + m0 + tid] : -1;
      gts[tid]  = v ? gateE[e * NTOK + m0 + tid] : 0.f;
    }
    __syncthreads();

    int tok0 = toks[ar];
    bool av = tok0 >= 0;
    const __bf16* aptr = h + (size_t)(av ? tok0 : 0) * FFN + ksp + ak;

    f32x4 acc[2][2] = {};
    LOADG2(0, 0);
    LOADG2(1, BK);
    for (int tt = 0; tt < 16; tt += 2) {
      STEP2(0, tt);
      STEP2(1, tt + 1);
    }

#pragma unroll
    for (int mf = 0; mf < 2; mf++) {
#pragma unroll
      for (int i = 0; i < 4; i++) {
        int row = wm * 32 + mf * 16 + (quad << 2) + i;
        int tok = toks[row];
        if (tok >= 0) {
          float g = gts[row];
          float* op = out + (size_t)tok * DM + n0 + wn * 32 + r16;
          __hip_atomic_fetch_add(op, acc[mf][0][i] * g,
                                 __ATOMIC_RELAXED, __HIP_MEMORY_SCOPE_AGENT);
          __hip_atomic_fetch_add(op + 16, acc[mf][1][i] * g,
                                 __ATOMIC_RELAXED, __HIP_MEMORY_SCOPE_AGENT);
        }
      }
    }
    __syncthreads();   // toks/gts/LDS reuse guard for next m-tile
  }
#undef STEP2
#undef LOADG2
}

extern "C" void kernel_launch(void* const* d_in, const int* in_sizes, int n_in,
                              void* d_out, int out_size, void* d_ws, size_t ws_size,
                              hipStream_t stream) {
  const float* x    = (const float*)d_in[0];
  const int*   mask = (const int*)d_in[1];
  const float* rw   = (const float*)d_in[2];
  const float* w1   = (const float*)d_in[3];
  const float* w2   = (const float*)d_in[4];
  float* out = (float*)d_out;

  char* ws = (char*)d_ws;
  int*    counts = (int*)ws;                                   // 1 KB
  int*    tlist  = (int*)(ws + 1024);                          // 64 KB
  float*  gateE  = (float*)(ws + 1024 + 65536);                // 64 KB
  __bf16* xg     = (__bf16*)(ws + 132096);                     // 32 MB compact bf16 x
  __bf16* h      = (__bf16*)(ws + 132096 +
                             (size_t)NEXP * NTOK * DM * 2);    // 16 MB dense h

  hipMemsetAsync(counts, 0, 1024, stream);
  hipMemsetAsync(out, 0, (size_t)out_size * sizeof(float), stream);

  router_gather<<<NTOK / 4, 256, 0, stream>>>(x, mask, rw, counts, tlist, gateE, xg);
  // 8 experts x 4 m-tile slots (BM=64, grid-stride) x 64 n-tiles = 2048 blocks
  moe_gemm1<<<NEXP * MTS * (FFN / BN), 256, 0, stream>>>(xg, w1, counts, tlist, h);
  // 4 K-splits x 8 experts x 4 m-tile slots x 16 n-tiles = 2048 blocks
  moe_gemm2<<<G2_SPLIT * NEXP * MTS * (DM / BN), 256, 0, stream>>>(
      h, w2, counts, tlist, gateE, out);
}

// Round 11
// 124.588 us; speedup vs baseline: 1.3762x; 1.3762x over previous
//
#include <hip/hip_runtime.h>
#include <hip/hip_bf16.h>

#define NTOK 2048      // B*T
#define DM 1024
#define NEXP 8
#define FFN 4096
#define BM 64
#define BN 64
#define BK 64
#define ASTR 72        // A-tile LDS row stride (bf16)
#define MT1 8          // m-tile slots (8*64=512 cap, grid-stride beyond)
#define G2_SPLIT 4

typedef __bf16 bf16x8 __attribute__((ext_vector_type(8)));
typedef __bf16 bf16x4 __attribute__((ext_vector_type(4)));
typedef float f32x4 __attribute__((ext_vector_type(4)));

__device__ __forceinline__ bf16x8 zero8() {
  bf16x8 z;
#pragma unroll
  for (int j = 0; j < 8; j++) z[j] = (__bf16)0.f;
  return z;
}

// Swizzled B-tile read (row stride 144 B, XOR 16B-block by row>>3): verified R5-R10.
__device__ __forceinline__ bf16x8 readB(const char* BsB, int row, int kh, int quad) {
  return *(const bf16x8*)(BsB + row * 144 +
                          ((((kh << 2) + quad) ^ (row >> 3)) << 4));
}

// B staging WITHOUT cross-lane transpose (new in R11):
// thread (w, quad, r16) loads rows k = kb + w*16 + quad*4 + j (j=0..3),
// cols n0 + r16*4 .. +3.  Column c's 4-long k-run = {br0[c],br1[c],br2[c],br3[c]}
// lives in-register; store bf16x4 to row (r16*4+c), 16B-block
// (w*2 + (quad>>1)) ^ rsw, inner 8B half (quad&1).  Read side unchanged.
#define STOREB4() do {                                                   \
    const float* p0 = (const float*)&br0;                                \
    const float* p1 = (const float*)&br1;                                \
    const float* p2 = (const float*)&br2;                                \
    const float* p3 = (const float*)&br3;                                \
    _Pragma("unroll") for (int c = 0; c < 4; ++c) {                      \
      bf16x4 o;                                                          \
      o[0] = (__bf16)p0[c]; o[1] = (__bf16)p1[c];                        \
      o[2] = (__bf16)p2[c]; o[3] = (__bf16)p3[c];                        \
      *(bf16x4*)(bb + c * 144) = o;                                      \
    } } while (0)

// ---------------- router + bf16 compact gather ----------------
__global__ __launch_bounds__(256) void router_gather(
    const float* __restrict__ x, const int* __restrict__ mask,
    const float* __restrict__ rw, int* __restrict__ counts,
    int* __restrict__ tlist, float* __restrict__ gateE,
    __bf16* __restrict__ xg)
{
  int wid = threadIdx.x >> 6, lane = threadIdx.x & 63;
  int t = blockIdx.x * 4 + wid;

  const float* xr = x + (size_t)t * DM;
  float xv[16];
#pragma unroll
  for (int i = 0; i < 4; i++) {
    const float4 v = *(const float4*)(xr + lane * 16 + i * 4);
    xv[i * 4 + 0] = v.x; xv[i * 4 + 1] = v.y;
    xv[i * 4 + 2] = v.z; xv[i * 4 + 3] = v.w;
  }

  float acc[NEXP];
#pragma unroll
  for (int e = 0; e < NEXP; e++) {
    float a = 0.f;
    const float* rwe = rw + e * DM + lane * 16;
#pragma unroll
    for (int i = 0; i < 4; i++) {
      const float4 r = *(const float4*)(rwe + i * 4);
      a += xv[i*4+0]*r.x + xv[i*4+1]*r.y + xv[i*4+2]*r.z + xv[i*4+3]*r.w;
    }
    acc[e] = a;
  }
#pragma unroll
  for (int e = 0; e < NEXP; e++)
#pragma unroll
    for (int s = 1; s < 64; s <<= 1) acc[e] += __shfl_xor(acc[e], s, 64);

  int pack = -1;
  if (lane == 0 && mask[t] != 0) {
    float m = acc[0]; int am = 0;
#pragma unroll
    for (int e = 1; e < NEXP; e++) if (acc[e] > m) { m = acc[e]; am = e; }
    float s = 0.f;
#pragma unroll
    for (int e = 0; e < NEXP; e++) s += __expf(acc[e] - m);
    int slot = atomicAdd(&counts[am], 1);
    tlist[am * NTOK + slot] = t;
    gateE[am * NTOK + slot] = 1.0f / s;
    pack = am * NTOK + slot;
  }
  pack = __shfl(pack, 0, 64);
  if (pack >= 0) {
    __bf16* dst = xg + (size_t)pack * DM + lane * 16;
    bf16x8 o0, o1;
#pragma unroll
    for (int j = 0; j < 8; j++) {
      o0[j] = (__bf16)xv[j];
      o1[j] = (__bf16)xv[8 + j];
    }
    *(bf16x8*)dst = o0;
    *(bf16x8*)(dst + 8) = o1;
  }
}

// ---------------- GEMM1: h[tok] = relu(xg_e @ w1[e]), BM=64 ----------------
__global__ __launch_bounds__(256) void moe_gemm1(
    const __bf16* __restrict__ xg, const float* __restrict__ w1,
    const int* __restrict__ counts, const int* __restrict__ tlist,
    __bf16* __restrict__ h)
{
  int bx = blockIdx.x;
  int nt = bx & 63, mt = (bx >> 6) & (MT1 - 1), e = bx >> 9;
  int cnt = counts[e];
  if (mt * BM >= cnt) return;
  int n0 = nt * BN;

  __shared__ __bf16 As[BM][ASTR];
  __shared__ char   Bs[64 * 144];
  __shared__ int    toks[BM];

  int tid = threadIdx.x, lane = tid & 63, w = tid >> 6;
  int wm = w >> 1, wn = w & 1;
  int r16 = lane & 15, quad = lane >> 4;
  int rsw = r16 >> 1;
  char* bb = Bs + (r16 << 2) * 144 +
             (((((w << 1) + (quad >> 1))) ^ rsw) << 4) + ((quad & 1) << 3);

  const __bf16* xge = xg + (size_t)e * NTOK * DM;
  const float*  w1e = w1 + (size_t)e * DM * FFN;

  int ar = tid >> 2;
  int ak = (tid & 3) << 4;
  // B rows: k = kb + w*16 + quad*4 + j, cols n0 + r16*4
  const float* bptr = w1e + (size_t)(w * 16 + quad * 4) * FFN + n0 + (r16 << 2);

  bf16x8 a0r, a1r;
  float4 br0, br1, br2, br3;

#define LOADG1(kb) do {                                                   \
    a0r = av ? *(const bf16x8*)(aptr + (kb))     : zero8();               \
    a1r = av ? *(const bf16x8*)(aptr + (kb) + 8) : zero8();               \
    br0 = *(const float4*)(bptr + (size_t)((kb) + 0) * FFN);              \
    br1 = *(const float4*)(bptr + (size_t)((kb) + 1) * FFN);              \
    br2 = *(const float4*)(bptr + (size_t)((kb) + 2) * FFN);              \
    br3 = *(const float4*)(bptr + (size_t)((kb) + 3) * FFN);              \
  } while (0)

  for (int m0 = mt * BM; m0 < cnt; m0 += MT1 * BM) {
    bool av = (m0 + ar) < cnt;
    const __bf16* aptr = xge + (size_t)(m0 + ar) * DM + ak;

    f32x4 acc[2][2] = {};
    LOADG1(0);
    const int T = DM / BK;   // 16
    for (int t = 0; t < T; t++) {
      *(bf16x8*)&As[ar][ak]     = a0r;
      *(bf16x8*)&As[ar][ak + 8] = a1r;
      STOREB4();
      __syncthreads();
      if (t + 1 < T) LOADG1((t + 1) * BK);   // in flight during MFMA phase
#pragma unroll
      for (int kh = 0; kh < 2; kh++) {
        int ks = kh * 32 + (quad << 3);
        bf16x8 aA = *(const bf16x8*)&As[wm * 32 + r16][ks];
        bf16x8 aB = *(const bf16x8*)&As[wm * 32 + 16 + r16][ks];
        bf16x8 bA = readB(Bs, wn * 32 + r16, kh, quad);
        bf16x8 bB = readB(Bs, wn * 32 + 16 + r16, kh, quad);
        acc[0][0] = __builtin_amdgcn_mfma_f32_16x16x32_bf16(aA, bA, acc[0][0], 0, 0, 0);
        acc[0][1] = __builtin_amdgcn_mfma_f32_16x16x32_bf16(aA, bB, acc[0][1], 0, 0, 0);
        acc[1][0] = __builtin_amdgcn_mfma_f32_16x16x32_bf16(aB, bA, acc[1][0], 0, 0, 0);
        acc[1][1] = __builtin_amdgcn_mfma_f32_16x16x32_bf16(aB, bB, acc[1][1], 0, 0, 0);
      }
      __syncthreads();
    }

    if (tid < BM) toks[tid] = (m0 + tid < cnt) ? tlist[e * NTOK + m0 + tid] : -1;
    __syncthreads();

#pragma unroll
    for (int mf = 0; mf < 2; mf++) {
#pragma unroll
      for (int i = 0; i < 4; i++) {
        int row = wm * 32 + mf * 16 + (quad << 2) + i;
        int tok = toks[row];
        if (tok >= 0) {
          __bf16* hp = h + (size_t)tok * FFN + n0 + wn * 32 + r16;
          hp[0]  = (__bf16)fmaxf(acc[mf][0][i], 0.f);
          hp[16] = (__bf16)fmaxf(acc[mf][1][i], 0.f);
        }
      }
    }
    __syncthreads();   // toks reuse guard for next m-tile
  }
#undef LOADG1
}

// ------- GEMM2 (split-K=4): out[tok] += (h_e @ w2[e]) * gate ----------
__global__ __launch_bounds__(256) void moe_gemm2(
    const __bf16* __restrict__ h, const float* __restrict__ w2,
    const int* __restrict__ counts, const int* __restrict__ tlist,
    const float* __restrict__ gateE, float* __restrict__ out)
{
  int bx = blockIdx.x;
  int nt = bx & 15, mt = (bx >> 4) & (MT1 - 1), e = (bx >> 7) & 7, sp = bx >> 10;
  int cnt = counts[e];
  if (mt * BM >= cnt) return;
  int n0 = nt * BN;
  int ksp = sp * (FFN / G2_SPLIT);

  __shared__ __bf16 As[BM][ASTR];
  __shared__ char   Bs[64 * 144];
  __shared__ int    toks[BM];
  __shared__ float  gts[BM];

  int tid = threadIdx.x, lane = tid & 63, w = tid >> 6;
  int wm = w >> 1, wn = w & 1;
  int r16 = lane & 15, quad = lane >> 4;
  int rsw = r16 >> 1;
  char* bb = Bs + (r16 << 2) * 144 +
             (((((w << 1) + (quad >> 1))) ^ rsw) << 4) + ((quad & 1) << 3);

  const float* w2e = w2 + (size_t)e * FFN * DM;
  int ar = tid >> 2;
  int ak = (tid & 3) << 4;
  const float* bptr = w2e + (size_t)(ksp + w * 16 + quad * 4) * DM + n0 + (r16 << 2);

  bf16x8 a0r, a1r;
  float4 br0, br1, br2, br3;

#define LOADG2(kb) do {                                                   \
    a0r = av ? *(const bf16x8*)(aptr + (kb))     : zero8();               \
    a1r = av ? *(const bf16x8*)(aptr + (kb) + 8) : zero8();               \
    br0 = *(const float4*)(bptr + (size_t)((kb) + 0) * DM);               \
    br1 = *(const float4*)(bptr + (size_t)((kb) + 1) * DM);               \
    br2 = *(const float4*)(bptr + (size_t)((kb) + 2) * DM);               \
    br3 = *(const float4*)(bptr + (size_t)((kb) + 3) * DM);               \
  } while (0)

  for (int m0 = mt * BM; m0 < cnt; m0 += MT1 * BM) {
    if (tid < BM) {
      bool v = (m0 + tid) < cnt;
      toks[tid] = v ? tlist[e * NTOK + m0 + tid] : -1;
      gts[tid]  = v ? gateE[e * NTOK + m0 + tid] : 0.f;
    }
    __syncthreads();

    int tok0 = toks[ar];
    bool av = tok0 >= 0;
    const __bf16* aptr = h + (size_t)(av ? tok0 : 0) * FFN + ksp + ak;

    f32x4 acc[2][2] = {};
    LOADG2(0);
    const int T = (FFN / G2_SPLIT) / BK;   // 16
    for (int t = 0; t < T; t++) {
      *(bf16x8*)&As[ar][ak]     = a0r;
      *(bf16x8*)&As[ar][ak + 8] = a1r;
      STOREB4();
      __syncthreads();
      if (t + 1 < T) LOADG2((t + 1) * BK);
#pragma unroll
      for (int kh = 0; kh < 2; kh++) {
        int ks = kh * 32 + (quad << 3);
        bf16x8 aA = *(const bf16x8*)&As[wm * 32 + r16][ks];
        bf16x8 aB = *(const bf16x8*)&As[wm * 32 + 16 + r16][ks];
        bf16x8 bA = readB(Bs, wn * 32 + r16, kh, quad);
        bf16x8 bB = readB(Bs, wn * 32 + 16 + r16, kh, quad);
        acc[0][0] = __builtin_amdgcn_mfma_f32_16x16x32_bf16(aA, bA, acc[0][0], 0, 0, 0);
        acc[0][1] = __builtin_amdgcn_mfma_f32_16x16x32_bf16(aA, bB, acc[0][1], 0, 0, 0);
        acc[1][0] = __builtin_amdgcn_mfma_f32_16x16x32_bf16(aB, bA, acc[1][0], 0, 0, 0);
        acc[1][1] = __builtin_amdgcn_mfma_f32_16x16x32_bf16(aB, bB, acc[1][1], 0, 0, 0);
      }
      __syncthreads();
    }

#pragma unroll
    for (int mf = 0; mf < 2; mf++) {
#pragma unroll
      for (int i = 0; i < 4; i++) {
        int row = wm * 32 + mf * 16 + (quad << 2) + i;
        int tok = toks[row];
        if (tok >= 0) {
          float g = gts[row];
          float* op = out + (size_t)tok * DM + n0 + wn * 32 + r16;
          __hip_atomic_fetch_add(op, acc[mf][0][i] * g,
                                 __ATOMIC_RELAXED, __HIP_MEMORY_SCOPE_AGENT);
          __hip_atomic_fetch_add(op + 16, acc[mf][1][i] * g,
                                 __ATOMIC_RELAXED, __HIP_MEMORY_SCOPE_AGENT);
        }
      }
    }
    __syncthreads();   // toks/gts reuse guard for next m-tile
  }
#undef LOADG2
}

extern "C" void kernel_launch(void* const* d_in, const int* in_sizes, int n_in,
                              void* d_out, int out_size, void* d_ws, size_t ws_size,
                              hipStream_t stream) {
  const float* x    = (const float*)d_in[0];
  const int*   mask = (const int*)d_in[1];
  const float* rw   = (const float*)d_in[2];
  const float* w1   = (const float*)d_in[3];
  const float* w2   = (const float*)d_in[4];
  float* out = (float*)d_out;

  char* ws = (char*)d_ws;
  int*    counts = (int*)ws;                                   // 1 KB
  int*    tlist  = (int*)(ws + 1024);                          // 64 KB
  float*  gateE  = (float*)(ws + 1024 + 65536);                // 64 KB
  __bf16* xg     = (__bf16*)(ws + 132096);                     // 32 MB compact bf16 x
  __bf16* h      = (__bf16*)(ws + 132096 +
                             (size_t)NEXP * NTOK * DM * 2);    // 16 MB dense h

  hipMemsetAsync(counts, 0, 1024, stream);
  hipMemsetAsync(out, 0, (size_t)out_size * sizeof(float), stream);

  router_gather<<<NTOK / 4, 256, 0, stream>>>(x, mask, rw, counts, tlist, gateE, xg);
  // 8 experts x 8 m-tile slots (BM=64, grid-stride) x 64 n-tiles = 4096 blocks
  moe_gemm1<<<NEXP * MT1 * (FFN / BN), 256, 0, stream>>>(xg, w1, counts, tlist, h);
  // 4 K-splits x 8 experts x 8 m-tile slots x 16 n-tiles = 4096 blocks
  moe_gemm2<<<G2_SPLIT * NEXP * MT1 * (DM / BN), 256, 0, stream>>>(
      h, w2, counts, tlist, gateE, out);
}